// Round 1
// baseline (23.292 us; speedup 1.0000x reference)
//
#include <hip/hip_runtime.h>

// Problem shape (fixed by reference setup_inputs)
constexpr int F = 2, B = 64, S = 512, D = 768;
constexpr int NCHUNK = 16;            // S-chunks per (f,b)
constexpr int SROWS = S / NCHUNK;     // 32 rows per block
constexpr int TPB = D / 4;            // 192 threads, one float4 column slice each
constexpr float EPS = 1e-9f;

// Phase 1: per (f,b,chunk) block computes partial T = sum_s mask[s] * (tok[s,:] . sent[:])
// via column accumulation: acc_d = sum_s mask[s]*tok[s,d]; partial = sum_d acc_d*sent_d.
__global__ __launch_bounds__(TPB) void nl_partial(
        const float* __restrict__ tok,   // [F*B, S, D]
        const float* __restrict__ sent,  // [F*B, D]
        const int*   __restrict__ mask,  // [F*B, S]
        float* __restrict__ ws)          // [F*B * NCHUNK]
{
    const int blk   = blockIdx.x;            // fb*NCHUNK + chunk
    const int fb    = blk / NCHUNK;
    const int chunk = blk - fb * NCHUNK;
    const int tid   = threadIdx.x;

    const float4 sv = reinterpret_cast<const float4*>(sent + (size_t)fb * D)[tid];
    const float* tbase = tok + (size_t)fb * S * D + (size_t)chunk * SROWS * D;
    const int*   mrow  = mask + (size_t)fb * S + chunk * SROWS;

    float4 acc = make_float4(0.f, 0.f, 0.f, 0.f);
#pragma unroll 4
    for (int s = 0; s < SROWS; ++s) {
        // mask is identical across the block -> wave-uniform branch; mask=0 rows
        // are never fetched from HBM (halves token traffic on random 0/1 mask).
        if (mrow[s] != 0) {
            float4 t = reinterpret_cast<const float4*>(tbase + (size_t)s * D)[tid];
            acc.x += t.x; acc.y += t.y; acc.z += t.z; acc.w += t.w;
        }
    }
    float p = acc.x * sv.x + acc.y * sv.y + acc.z * sv.z + acc.w * sv.w;

    // wave (64-lane) reduce, then cross-wave via LDS (3 waves)
#pragma unroll
    for (int off = 32; off > 0; off >>= 1) p += __shfl_down(p, off, 64);
    __shared__ float sm[TPB / 64];
    const int wave = tid >> 6, lane = tid & 63;
    if (lane == 0) sm[wave] = p;
    __syncthreads();
    if (tid == 0) ws[blk] = sm[0] + sm[1] + sm[2];
}

// Phase 2: one block; thread t owns (f,b)=t, sums its NCHUNK partials,
// applies T/(T+EPS), block-reduces, writes scalar out = sum / F.
__global__ __launch_bounds__(128) void nl_finalize(
        const float* __restrict__ ws, float* __restrict__ out)
{
    const int t = threadIdx.x;               // 128 = F*B threads
    float T = 0.f;
#pragma unroll
    for (int c = 0; c < NCHUNK; ++c) T += ws[t * NCHUNK + c];
    float v = T / (T + EPS);
#pragma unroll
    for (int off = 32; off > 0; off >>= 1) v += __shfl_down(v, off, 64);
    __shared__ float sm[2];
    if ((t & 63) == 0) sm[t >> 6] = v;
    __syncthreads();
    if (t == 0) out[0] = (sm[0] + sm[1]) * (1.0f / (float)F);
}

extern "C" void kernel_launch(void* const* d_in, const int* in_sizes, int n_in,
                              void* d_out, int out_size, void* d_ws, size_t ws_size,
                              hipStream_t stream) {
    const float* tok  = (const float*)d_in[0];
    const float* sent = (const float*)d_in[1];
    const int*   mask = (const int*)d_in[2];
    float* out = (float*)d_out;
    float* ws  = (float*)d_ws;   // needs F*B*NCHUNK*4 = 8 KiB

    nl_partial<<<F * B * NCHUNK, TPB, 0, stream>>>(tok, sent, mask, ws);
    nl_finalize<<<1, 128, 0, stream>>>(ws, out);
}

// Round 2
// 23.242 us; speedup vs baseline: 1.0022x; 1.0022x over previous
//
#include <hip/hip_runtime.h>

// Problem shape (fixed by reference setup_inputs)
constexpr int F = 2, B = 64, S = 512, D = 768;
constexpr int NCHUNK = 16;            // S-chunks per (f,b)
constexpr int SROWS = S / NCHUNK;     // 32 rows per block (== ballot width)
constexpr int TPB = D / 4;            // 192 threads, one float4 column slice each
constexpr float EPS = 1e-9f;

// Phase 1: per (f,b,chunk) block computes partial T = sum_s mask[s] * (tok[s,:] . sent[:])
// via column accumulation. Active rows are compacted into an LDS index list first
// (ballot + prefix-popcount), so the load loop is dense and branch-free -> the
// compiler keeps multiple float4 loads in flight (latency hiding), instead of
// one-load-per-uniform-branch serialization.
__global__ __launch_bounds__(TPB) void nl_partial(
        const float* __restrict__ tok,   // [F*B, S, D]
        const float* __restrict__ sent,  // [F*B, D]
        const int*   __restrict__ mask,  // [F*B, S]
        float* __restrict__ ws)          // [F*B * NCHUNK]
{
    const int blk   = blockIdx.x;            // fb*NCHUNK + chunk
    const int fb    = blk / NCHUNK;
    const int chunk = blk - fb * NCHUNK;
    const int tid   = threadIdx.x;
    const int lane  = tid & 63;

    __shared__ int idxs[SROWS];
    __shared__ int nact;
    __shared__ float sm[TPB / 64];

    // sent fragment (independent load, issued early)
    const float4 sv = reinterpret_cast<const float4*>(sent + (size_t)fb * D)[tid];

    // --- build active-row list (rows with mask != 0), uniform across block ---
    const int* mrow = mask + (size_t)fb * S + chunk * SROWS;
    int mv = 0;
    if (lane < SROWS) mv = mrow[lane];
    unsigned long long bal = __ballot(mv != 0);   // same value in every wave
    if (tid < 64) {                               // wave 0 writes the list
        if (mv != 0) {
            int pos = __popcll(bal & ((1ull << lane) - 1ull));
            idxs[pos] = lane;
        }
        if (lane == 0) nact = __popcll(bal);
    }
    __syncthreads();
    const int n = nact;

    // --- dense, branch-free masked column accumulation ---
    const float* tbase = tok + (size_t)fb * S * D + (size_t)chunk * SROWS * D;
    float4 acc = make_float4(0.f, 0.f, 0.f, 0.f);
#pragma unroll 4
    for (int j = 0; j < n; ++j) {
        const int s = idxs[j];
        float4 t = reinterpret_cast<const float4*>(tbase + (size_t)s * D)[tid];
        acc.x += t.x; acc.y += t.y; acc.z += t.z; acc.w += t.w;
    }
    float p = acc.x * sv.x + acc.y * sv.y + acc.z * sv.z + acc.w * sv.w;

    // wave (64-lane) reduce, then cross-wave via LDS (3 waves)
#pragma unroll
    for (int off = 32; off > 0; off >>= 1) p += __shfl_down(p, off, 64);
    const int wave = tid >> 6;
    if (lane == 0) sm[wave] = p;
    __syncthreads();
    if (tid == 0) ws[blk] = sm[0] + sm[1] + sm[2];
}

// Phase 2: one block; thread t owns (f,b)=t, sums its NCHUNK partials,
// applies T/(T+EPS), block-reduces, writes scalar out = sum / F.
__global__ __launch_bounds__(128) void nl_finalize(
        const float* __restrict__ ws, float* __restrict__ out)
{
    const int t = threadIdx.x;               // 128 = F*B threads
    float T = 0.f;
#pragma unroll
    for (int c = 0; c < NCHUNK; ++c) T += ws[t * NCHUNK + c];
    float v = T / (T + EPS);
#pragma unroll
    for (int off = 32; off > 0; off >>= 1) v += __shfl_down(v, off, 64);
    __shared__ float sm[2];
    if ((t & 63) == 0) sm[t >> 6] = v;
    __syncthreads();
    if (t == 0) out[0] = (sm[0] + sm[1]) * (1.0f / (float)F);
}

extern "C" void kernel_launch(void* const* d_in, const int* in_sizes, int n_in,
                              void* d_out, int out_size, void* d_ws, size_t ws_size,
                              hipStream_t stream) {
    const float* tok  = (const float*)d_in[0];
    const float* sent = (const float*)d_in[1];
    const int*   mask = (const int*)d_in[2];
    float* out = (float*)d_out;
    float* ws  = (float*)d_ws;   // needs F*B*NCHUNK*4 = 8 KiB

    nl_partial<<<F * B * NCHUNK, TPB, 0, stream>>>(tok, sent, mask, ws);
    nl_finalize<<<1, 128, 0, stream>>>(ws, out);
}